// Round 2
// baseline (6387.826 us; speedup 1.0000x reference)
//
#include <hip/hip_runtime.h>
#include <cstdint>
#include <cstddef>

#define D_MODEL 512
#define D_STATE 16
#define D_INNER 1024
#define DT_RANK 32
#define D_CONV 4
#define N_LAYERS 4
#define NUM_LEADS 12
#define BATCH 8
#define SEQLEN 2500
#define BL (BATCH*SEQLEN)   // 20000
#define NC 25               // scan chunks per sequence
#define CH 100              // steps per chunk (NC*CH == SEQLEN)

__device__ __forceinline__ float softplus_f(float x){
    return x > 0.f ? x + log1pf(expf(-x)) : log1pf(expf(x));
}
__device__ __forceinline__ float silu_f(float x){
    return x / (1.f + expf(-x));
}

// ---------------- projection: x[b,l,d] = sum_c ecg[b,c,l]*Wp[d,c] + bp[d] ----------------
__global__ __launch_bounds__(256) void proj_kernel(const float* __restrict__ ecg,
                                                   const float* __restrict__ Wp,
                                                   const float* __restrict__ bp,
                                                   float* __restrict__ x)
{
    int idx = blockIdx.x*256 + threadIdx.x;      // over BL*512
    int d  = idx & 511;
    int bl = idx >> 9;
    if (bl >= BL) return;
    int b = bl / SEQLEN, l = bl % SEQLEN;
    const float* e = ecg + (size_t)b*NUM_LEADS*SEQLEN + l;
    const float* w = Wp + d*NUM_LEADS;
    float acc = bp[d];
    #pragma unroll
    for (int c=0;c<NUM_LEADS;c++) acc += e[(size_t)c*SEQLEN]*w[c];
    x[idx] = acc;
}

// ---------------- generic f32 GEMM: C[M,N] = act(A[M,K(lda)] * W[N,K]^T + bias) ----------------
// ACT: 0 = none, 1 = bias + softplus
template<int ACT>
__global__ __launch_bounds__(256) void gemm_f32(const float* __restrict__ A, int lda,
                                                const float* __restrict__ W,
                                                const float* __restrict__ bias,
                                                float* __restrict__ C,
                                                int M, int N, int K)
{
    constexpr int BM=128, BN=64, BK=16;
    __shared__ float As[BK][BM+4];
    __shared__ float Ws[BK][BN+4];
    const int tid = threadIdx.x;
    const int row0 = blockIdx.y*BM;
    const int col0 = blockIdx.x*BN;
    const int ty = tid>>4, tx = tid&15;      // 16x16 threads, each 8x4 outputs
    const int lr = tid>>2;                   // 0..63
    const int lk = (tid&3)<<2;               // 0,4,8,12
    float acc[8][4] = {};

    for (int kk=0; kk<K; kk+=BK) {
        #pragma unroll
        for (int h=0; h<2; ++h) {
            int r = lr + h*64;
            int gr = row0 + r;
            float4 v = make_float4(0.f,0.f,0.f,0.f);
            if (gr < M) v = *(const float4*)(A + (size_t)gr*lda + kk + lk);
            As[lk+0][r]=v.x; As[lk+1][r]=v.y; As[lk+2][r]=v.z; As[lk+3][r]=v.w;
        }
        {
            int gc = col0 + lr;              // N % 64 == 0 for all our GEMMs
            float4 v = *(const float4*)(W + (size_t)gc*K + kk + lk);
            Ws[lk+0][lr]=v.x; Ws[lk+1][lr]=v.y; Ws[lk+2][lr]=v.z; Ws[lk+3][lr]=v.w;
        }
        __syncthreads();
        #pragma unroll
        for (int k=0;k<BK;k++){
            float4 a0 = *(const float4*)&As[k][ty*8];
            float4 a1 = *(const float4*)&As[k][ty*8+4];
            float4 bv = *(const float4*)&Ws[k][tx*4];
            float a[8] = {a0.x,a0.y,a0.z,a0.w,a1.x,a1.y,a1.z,a1.w};
            float bb[4] = {bv.x,bv.y,bv.z,bv.w};
            #pragma unroll
            for (int i=0;i<8;i++)
                #pragma unroll
                for (int j=0;j<4;j++)
                    acc[i][j] += a[i]*bb[j];
        }
        __syncthreads();
    }
    #pragma unroll
    for (int i=0;i<8;i++){
        int gr = row0 + ty*8 + i;
        if (gr >= M) continue;
        float4 o;
        float* op = &o.x;
        #pragma unroll
        for (int j=0;j<4;j++){
            int gc = col0 + tx*4 + j;
            float v = acc[i][j];
            if (ACT==1) v = softplus_f(v + bias[gc]);
            op[j] = v;
        }
        *(float4*)(C + (size_t)gr*N + col0 + tx*4) = o;
    }
}

// ---------------- causal depthwise conv (taps l-3..l) + silu; input stride 1024 ----------------
__global__ __launch_bounds__(256) void conv_silu_kernel(const float* __restrict__ xin,
                                                        const float* __restrict__ w,   // [E][4]
                                                        const float* __restrict__ cb,  // [E]
                                                        float* __restrict__ xc, int M)
{
    int idx = blockIdx.x*256 + threadIdx.x;   // M*1024
    int e  = idx & 1023;
    int bl = idx >> 10;
    if (bl >= M) return;
    int l = bl % SEQLEN;                      // chunks are whole batches
    float acc = cb[e];
    #pragma unroll
    for (int k=0;k<D_CONV;k++){
        int dl = k - (D_CONV-1);
        if (l + dl >= 0) acc += xin[(size_t)(bl+dl)*1024 + e] * w[e*4+k];
    }
    xc[idx] = silu_f(acc);
}

// ---------------- scan pass A: per-chunk local scan from h=0; store final state S and product P ----------------
__global__ __launch_bounds__(256) void scan_a(const float* __restrict__ dt,
                                              const float* __restrict__ xc,
                                              const float* __restrict__ dbc,
                                              const float* __restrict__ A_log,
                                              float* __restrict__ S, float* __restrict__ P)
{
    int e = blockIdx.x*256 + threadIdx.x;   // 0..1023
    int c = blockIdx.y, b = blockIdx.z;     // b = batch LOCAL to this chunk launch
    float Ae[16], h[16], Pr[16];
    #pragma unroll
    for (int s=0;s<16;s++){ Ae[s] = -expf(A_log[e*16+s]); h[s]=0.f; Pr[s]=1.f; }
    int bl0 = b*SEQLEN + c*CH;
    for (int t=0;t<CH;t++){
        size_t bl = bl0 + t;
        float dtv = dt[bl*1024 + e];
        float xv  = xc[bl*1024 + e];
        float dtx = dtv*xv;
        const float* bc = dbc + bl*64 + DT_RANK;
        #pragma unroll
        for (int s=0;s<16;s++){
            float a = __expf(dtv*Ae[s]);
            h[s] = h[s]*a + dtx*bc[s];
            Pr[s] *= a;
        }
    }
    size_t base = ((size_t)(b*NC + c)*16)*1024 + e;
    #pragma unroll
    for (int s=0;s<16;s++){ S[base + (size_t)s*1024] = h[s]; P[base + (size_t)s*1024] = Pr[s]; }
}

// ---------------- scan pass M: sequential combine over chunks -> initial state per chunk ----------------
__global__ __launch_bounds__(256) void scan_m(const float* __restrict__ S,
                                              const float* __restrict__ P,
                                              float* __restrict__ H0)
{
    int idx = blockIdx.x*256 + threadIdx.x;  // NBC*16*1024
    int e = idx & 1023;
    int s = (idx >> 10) & 15;
    int b = idx >> 14;
    float h = 0.f;
    for (int c=0;c<NC;c++){
        size_t off = ((size_t)(b*NC+c)*16 + s)*1024 + e;
        H0[off] = h;
        h = S[off] + P[off]*h;
    }
}

// ---------------- scan pass B: real scan with chunk initial states; fused D-skip + silu(z) gate ----------------
// y aliases dt (read element then overwrite same element) — safe.
__global__ __launch_bounds__(256) void scan_b(const float* dt_in,
                                              const float* __restrict__ xc,
                                              const float* __restrict__ dbc,
                                              const float* __restrict__ z,      // stride 1024
                                              const float* __restrict__ A_log,
                                              const float* __restrict__ Dpv,
                                              const float* __restrict__ H0,
                                              float* y)
{
    int e = blockIdx.x*256 + threadIdx.x;
    int c = blockIdx.y, b = blockIdx.z;
    float Ae[16], h[16];
    size_t base = ((size_t)(b*NC + c)*16)*1024 + e;
    #pragma unroll
    for (int s=0;s<16;s++){ Ae[s] = -expf(A_log[e*16+s]); h[s] = H0[base + (size_t)s*1024]; }
    float dpe = Dpv[e];
    int bl0 = b*SEQLEN + c*CH;
    for (int t=0;t<CH;t++){
        size_t bl = bl0 + t;
        float dtv = dt_in[bl*1024 + e];
        float xv  = xc[bl*1024 + e];
        float dtx = dtv*xv;
        const float* bc = dbc + bl*64 + DT_RANK;
        float yv = 0.f;
        #pragma unroll
        for (int s=0;s<16;s++){
            float a = __expf(dtv*Ae[s]);
            h[s] = h[s]*a + dtx*bc[s];
            yv += h[s]*bc[16+s];
        }
        yv += dpe*xv;
        float zv = z[bl*1024 + e];
        y[bl*1024 + e] = yv * silu_f(zv);
    }
}

// ---------------- LayerNorm over D=512 (two-pass, matches mean/var semantics; in-place safe) ----------------
__global__ __launch_bounds__(256) void layernorm_kernel(const float* __restrict__ x,
                                                        const float* __restrict__ g,
                                                        const float* __restrict__ bta,
                                                        float* __restrict__ out)
{
    int row = blockIdx.x;
    int tid = threadIdx.x;
    const float* xr = x + (size_t)row*512;
    float v0 = xr[tid], v1 = xr[tid+256];
    float s = v0 + v1;
    #pragma unroll
    for (int off=32; off>0; off>>=1) s += __shfl_down(s, off);
    __shared__ float red[8];
    int wid = tid>>6, lane = tid&63;
    if (lane==0) red[wid] = s;
    __syncthreads();
    if (tid==0){ float t=0; for(int i=0;i<4;i++) t+=red[i]; red[4] = t*(1.f/512.f); }
    __syncthreads();
    float m = red[4];
    float d0 = v0-m, d1 = v1-m;
    float q = d0*d0 + d1*d1;
    #pragma unroll
    for (int off=32; off>0; off>>=1) q += __shfl_down(q, off);
    if (lane==0) red[wid] = q;
    __syncthreads();
    if (tid==0){ float t=0; for(int i=0;i<4;i++) t+=red[i]; red[5] = t*(1.f/512.f); }
    __syncthreads();
    float inv = 1.f / sqrtf(red[5] + 1e-5f);
    out[(size_t)row*512 + tid]     = d0*inv*g[tid]     + bta[tid];
    out[(size_t)row*512 + tid+256] = d1*inv*g[tid+256] + bta[tid+256];
}

extern "C" void kernel_launch(void* const* d_in, const int* in_sizes, int n_in,
                              void* d_out, int out_size, void* d_ws, size_t ws_size,
                              hipStream_t stream)
{
    const float* ecg  = (const float*)d_in[0];
    const float* Wp   = (const float*)d_in[1];
    const float* bp   = (const float*)d_in[2];
    const float* Win  = (const float*)d_in[3];
    const float* convw= (const float*)d_in[4];
    const float* convb= (const float*)d_in[5];
    const float* Wx   = (const float*)d_in[6];
    const float* Wdt  = (const float*)d_in[7];
    const float* bdt  = (const float*)d_in[8];
    const float* A_log= (const float*)d_in[9];
    const float* Dp   = (const float*)d_in[10];
    const float* Wout = (const float*)d_in[11];
    const float* ln_g = (const float*)d_in[12];
    const float* ln_b = (const float*)d_in[13];
    float* out = (float*)d_out;   // also serves as the persistent x buffer (B,L,512)

    // ---- choose batch-chunk size so scratch fits ws_size ----
    // per-chunk floats: NBC*2500*(3*1024 + 64) + 3*NBC*NC*16*1024 = NBC*9,068,800
    int NBC = 8;
    while (NBC > 1 && (size_t)NBC*9068800ull*4ull > ws_size) NBC >>= 1;

    float* ws  = (float*)d_ws;
    size_t MT  = (size_t)NBC*SEQLEN;      // tokens per chunk
    float* Ab  = ws;                      // MT*1024   (x_conv pre-act, then z)
    float* Bx  = Ab + MT*1024;            // MT*1024   (xc)
    float* Cb  = Bx + MT*1024;            // MT*1024   (dt, then y in-place)
    float* dbc = Cb + MT*1024;            // MT*64
    float* Sb  = dbc + MT*64;             // NBC*409600
    float* Pb  = Sb + (size_t)NBC*409600; // NBC*409600
    float* H0  = Pb + (size_t)NBC*409600; // NBC*409600

    proj_kernel<<<(BL*512)/256,256,0,stream>>>(ecg, Wp, bp, out);

    const int M = NBC*SEQLEN;
    const int mtiles = (M+127)/128;

    for (int l=0; l<N_LAYERS; ++l) {
        const float* Winl = Win + (size_t)l*2048*512;
        for (int b0=0; b0<BATCH; b0+=NBC) {
            float* xchunk = out + (size_t)b0*SEQLEN*512;
            // 1) x_conv pre-activation = x @ Win[0:1024]^T
            gemm_f32<0><<<dim3(1024/64, mtiles),256,0,stream>>>(xchunk, 512,
                Winl, nullptr, Ab, M, 1024, 512);
            // 2) xc = silu(causal dwconv(x_conv))
            conv_silu_kernel<<<(M*1024)/256,256,0,stream>>>(Ab,
                convw + (size_t)l*1024*4, convb + (size_t)l*1024, Bx, M);
            // 3) z = x @ Win[1024:2048]^T  (reuse Ab)
            gemm_f32<0><<<dim3(1024/64, mtiles),256,0,stream>>>(xchunk, 512,
                Winl + (size_t)1024*512, nullptr, Ab, M, 1024, 512);
            // 4) dbc = xc @ Wx^T
            gemm_f32<0><<<dim3(64/64, mtiles),256,0,stream>>>(Bx, 1024,
                Wx + (size_t)l*64*1024, nullptr, dbc, M, 64, 1024);
            // 5) dt = softplus(dbc[:, :32] @ Wdt^T + bdt)
            gemm_f32<1><<<dim3(1024/64, mtiles),256,0,stream>>>(dbc, 64,
                Wdt + (size_t)l*1024*32, bdt + (size_t)l*1024, Cb, M, 1024, 32);
            // 6) chunk-parallel selective scan + D-skip + silu(z) gate
            scan_a<<<dim3(4,NC,NBC),256,0,stream>>>(Cb, Bx, dbc,
                A_log + (size_t)l*1024*16, Sb, Pb);
            scan_m<<<NBC*64,256,0,stream>>>(Sb, Pb, H0);
            scan_b<<<dim3(4,NC,NBC),256,0,stream>>>(Cb, Bx, dbc, Ab,
                A_log + (size_t)l*1024*16, Dp + (size_t)l*1024, H0, Cb);
            // 7) x = y @ Wout^T
            gemm_f32<0><<<dim3(512/64, mtiles),256,0,stream>>>(Cb, 1024,
                Wout + (size_t)l*512*1024, nullptr, xchunk, M, 512, 1024);
            // 8) LayerNorm in place
            layernorm_kernel<<<M,256,0,stream>>>(xchunk, ln_g + (size_t)l*512,
                ln_b + (size_t)l*512, xchunk);
        }
    }
}

// Round 3
// 4977.097 us; speedup vs baseline: 1.2834x; 1.2834x over previous
//
#include <hip/hip_runtime.h>
#include <cstdint>
#include <cstddef>

#define D_MODEL 512
#define D_STATE 16
#define D_INNER 1024
#define DT_RANK 32
#define D_CONV 4
#define N_LAYERS 4
#define NUM_LEADS 12
#define BATCH 8
#define SEQLEN 2500
#define BL (BATCH*SEQLEN)   // 20000
#define NC 25               // scan chunks per sequence
#define CH 100              // steps per chunk (NC*CH == SEQLEN)

typedef __attribute__((ext_vector_type(8))) short bf16x8;
typedef __attribute__((ext_vector_type(4))) float f32x4;

__device__ __forceinline__ float softplus_f(float x){
    return x > 0.f ? x + log1pf(expf(-x)) : log1pf(expf(x));
}
__device__ __forceinline__ float silu_f(float x){
    return x / (1.f + expf(-x));
}

// ---------------- projection: x[b,l,d] = sum_c ecg[b,c,l]*Wp[d,c] + bp[d] ----------------
__global__ __launch_bounds__(256) void proj_kernel(const float* __restrict__ ecg,
                                                   const float* __restrict__ Wp,
                                                   const float* __restrict__ bp,
                                                   float* __restrict__ x)
{
    int idx = blockIdx.x*256 + threadIdx.x;      // over BL*512
    int d  = idx & 511;
    int bl = idx >> 9;
    if (bl >= BL) return;
    int b = bl / SEQLEN, l = bl % SEQLEN;
    const float* e = ecg + (size_t)b*NUM_LEADS*SEQLEN + l;
    const float* w = Wp + d*NUM_LEADS;
    float acc = bp[d];
    #pragma unroll
    for (int c=0;c<NUM_LEADS;c++) acc += e[(size_t)c*SEQLEN]*w[c];
    x[idx] = acc;
}

// ---------------- split-bf16 MFMA GEMM: C[M,N] = A[M,K] * W[N,K]^T ----------------
// A, W, C all f32 in global. Internally A,W are split into bf16 hi/lo
// (x = hi + lo, ~16 mantissa bits) and accumulated with 3 MFMA terms:
// Ah*Wh + Ah*Wl + Al*Wh. Tile 128x128, BK=64, 4 waves (each 64x64 output).
__device__ __forceinline__ void split_store(ushort* __restrict__ Hi, ushort* __restrict__ Lo,
                                            int idx, float4 v)
{
    uint u0=__float_as_uint(v.x), u1=__float_as_uint(v.y);
    uint u2=__float_as_uint(v.z), u3=__float_as_uint(v.w);
    float h0=__uint_as_float(u0&0xffff0000u), h1=__uint_as_float(u1&0xffff0000u);
    float h2=__uint_as_float(u2&0xffff0000u), h3=__uint_as_float(u3&0xffff0000u);
    uint l0=__float_as_uint(v.x-h0)>>16, l1=__float_as_uint(v.y-h1)>>16;
    uint l2=__float_as_uint(v.z-h2)>>16, l3=__float_as_uint(v.w-h3)>>16;
    uint2 hp = make_uint2((u0>>16)|(u1&0xffff0000u), (u2>>16)|(u3&0xffff0000u));
    uint2 lp = make_uint2(l0|(l1<<16), l2|(l3<<16));
    *(uint2*)&Hi[idx] = hp;
    *(uint2*)&Lo[idx] = lp;
}

__global__ __launch_bounds__(256,2) void gemm_bf16x2(const float* __restrict__ A,
                                                     const float* __restrict__ W,
                                                     float* __restrict__ C,
                                                     int M, int N, int K)
{
    __shared__ ushort Ah[128*64];
    __shared__ ushort Al[128*64];
    __shared__ ushort Wh[128*64];
    __shared__ ushort Wl[128*64];
    const int tid  = threadIdx.x;
    const int row0 = blockIdx.y*128;
    const int col0 = blockIdx.x*128;
    const int wid  = tid>>6, lane = tid&63;
    const int wr = wid>>1, wc = wid&1;
    const int l15 = lane&15, l4 = lane>>4;

    f32x4 zero = {0.f,0.f,0.f,0.f};
    f32x4 acc[4][4];
    #pragma unroll
    for (int i=0;i<4;i++)
        #pragma unroll
        for (int j=0;j<4;j++) acc[i][j] = zero;

    for (int kk=0; kk<K; kk+=64) {
        // ---- stage: load f32 tiles, split to bf16 hi/lo, swizzled LDS store ----
        #pragma unroll
        for (int i=0;i<8;i++){
            int f4 = i*256 + tid;          // 0..2047
            int r  = f4>>4;                // 0..127
            int c4 = f4&15;                // float4 index within 64-wide row
            int sp = (c4>>1) ^ (r&7);      // swizzled 8-elem slot
            int idx = r*64 + sp*8 + (c4&1)*4;
            int gr = row0 + r;
            float4 va = make_float4(0.f,0.f,0.f,0.f);
            if (gr < M) va = *(const float4*)(A + (size_t)gr*K + kk + c4*4);
            split_store(Ah, Al, idx, va);
            float4 vw = *(const float4*)(W + (size_t)(col0+r)*K + kk + c4*4);
            split_store(Wh, Wl, idx, vw);
        }
        __syncthreads();
        // ---- compute: 2 K-steps of 32, 16 frags/wave, 3 MFMA terms ----
        #pragma unroll
        for (int ks=0; ks<2; ks++){
            bf16x8 ah[4], al[4], bh[4], bl[4];
            #pragma unroll
            for (int i=0;i<4;i++){
                int r = wr*64 + i*16 + l15;
                int sp = (ks*4 + l4) ^ (r&7);
                int idx = r*64 + sp*8;
                ah[i] = *(const bf16x8*)&Ah[idx];
                al[i] = *(const bf16x8*)&Al[idx];
            }
            #pragma unroll
            for (int j=0;j<4;j++){
                int r = wc*64 + j*16 + l15;
                int sp = (ks*4 + l4) ^ (r&7);
                int idx = r*64 + sp*8;
                bh[j] = *(const bf16x8*)&Wh[idx];
                bl[j] = *(const bf16x8*)&Wl[idx];
            }
            #pragma unroll
            for (int i=0;i<4;i++)
                #pragma unroll
                for (int j=0;j<4;j++){
                    acc[i][j] = __builtin_amdgcn_mfma_f32_16x16x32_bf16(ah[i], bh[j], acc[i][j], 0,0,0);
                    acc[i][j] = __builtin_amdgcn_mfma_f32_16x16x32_bf16(ah[i], bl[j], acc[i][j], 0,0,0);
                    acc[i][j] = __builtin_amdgcn_mfma_f32_16x16x32_bf16(al[i], bh[j], acc[i][j], 0,0,0);
                }
        }
        __syncthreads();
    }
    // ---- epilogue: D layout col=lane&15, row=(lane>>4)*4+reg ----
    #pragma unroll
    for (int i=0;i<4;i++){
        int rb = row0 + wr*64 + i*16 + l4*4;
        #pragma unroll
        for (int j=0;j<4;j++){
            int gc = col0 + wc*64 + j*16 + l15;
            #pragma unroll
            for (int q=0;q<4;q++){
                int grow = rb + q;
                if (grow < M) C[(size_t)grow*N + gc] = acc[i][j][q];
            }
        }
    }
}

// ---------------- generic f32 GEMM: C[M,N] = act(A[M,K(lda)] * W[N,K]^T + bias) ----------------
// ACT: 0 = none, 1 = bias + softplus   (kept for the small dbc / dt GEMMs)
template<int ACT>
__global__ __launch_bounds__(256) void gemm_f32(const float* __restrict__ A, int lda,
                                                const float* __restrict__ W,
                                                const float* __restrict__ bias,
                                                float* __restrict__ C,
                                                int M, int N, int K)
{
    constexpr int BM=128, BN=64, BK=16;
    __shared__ float As[BK][BM+4];
    __shared__ float Ws[BK][BN+4];
    const int tid = threadIdx.x;
    const int row0 = blockIdx.y*BM;
    const int col0 = blockIdx.x*BN;
    const int ty = tid>>4, tx = tid&15;
    const int lr = tid>>2;
    const int lk = (tid&3)<<2;
    float acc[8][4] = {};

    for (int kk=0; kk<K; kk+=BK) {
        #pragma unroll
        for (int h=0; h<2; ++h) {
            int r = lr + h*64;
            int gr = row0 + r;
            float4 v = make_float4(0.f,0.f,0.f,0.f);
            if (gr < M) v = *(const float4*)(A + (size_t)gr*lda + kk + lk);
            As[lk+0][r]=v.x; As[lk+1][r]=v.y; As[lk+2][r]=v.z; As[lk+3][r]=v.w;
        }
        {
            int gc = col0 + lr;
            float4 v = *(const float4*)(W + (size_t)gc*K + kk + lk);
            Ws[lk+0][lr]=v.x; Ws[lk+1][lr]=v.y; Ws[lk+2][lr]=v.z; Ws[lk+3][lr]=v.w;
        }
        __syncthreads();
        #pragma unroll
        for (int k=0;k<BK;k++){
            float4 a0 = *(const float4*)&As[k][ty*8];
            float4 a1 = *(const float4*)&As[k][ty*8+4];
            float4 bv = *(const float4*)&Ws[k][tx*4];
            float a[8] = {a0.x,a0.y,a0.z,a0.w,a1.x,a1.y,a1.z,a1.w};
            float bb[4] = {bv.x,bv.y,bv.z,bv.w};
            #pragma unroll
            for (int i=0;i<8;i++)
                #pragma unroll
                for (int j=0;j<4;j++)
                    acc[i][j] += a[i]*bb[j];
        }
        __syncthreads();
    }
    #pragma unroll
    for (int i=0;i<8;i++){
        int gr = row0 + ty*8 + i;
        if (gr >= M) continue;
        float4 o;
        float* op = &o.x;
        #pragma unroll
        for (int j=0;j<4;j++){
            int gc = col0 + tx*4 + j;
            float v = acc[i][j];
            if (ACT==1) v = softplus_f(v + bias[gc]);
            op[j] = v;
        }
        *(float4*)(C + (size_t)gr*N + col0 + tx*4) = o;
    }
}

// ---------------- causal depthwise conv (taps l-3..l) + silu; input stride 1024 ----------------
__global__ __launch_bounds__(256) void conv_silu_kernel(const float* __restrict__ xin,
                                                        const float* __restrict__ w,
                                                        const float* __restrict__ cb,
                                                        float* __restrict__ xc, int M)
{
    int idx = blockIdx.x*256 + threadIdx.x;
    int e  = idx & 1023;
    int bl = idx >> 10;
    if (bl >= M) return;
    int l = bl % SEQLEN;
    float acc = cb[e];
    #pragma unroll
    for (int k=0;k<D_CONV;k++){
        int dl = k - (D_CONV-1);
        if (l + dl >= 0) acc += xin[(size_t)(bl+dl)*1024 + e] * w[e*4+k];
    }
    xc[idx] = silu_f(acc);
}

// ---------------- scan pass A ----------------
__global__ __launch_bounds__(256) void scan_a(const float* __restrict__ dt,
                                              const float* __restrict__ xc,
                                              const float* __restrict__ dbc,
                                              const float* __restrict__ A_log,
                                              float* __restrict__ S, float* __restrict__ P)
{
    int e = blockIdx.x*256 + threadIdx.x;
    int c = blockIdx.y, b = blockIdx.z;
    float Ae[16], h[16], Pr[16];
    #pragma unroll
    for (int s=0;s<16;s++){ Ae[s] = -expf(A_log[e*16+s]); h[s]=0.f; Pr[s]=1.f; }
    int bl0 = b*SEQLEN + c*CH;
    for (int t=0;t<CH;t++){
        size_t bl = bl0 + t;
        float dtv = dt[bl*1024 + e];
        float xv  = xc[bl*1024 + e];
        float dtx = dtv*xv;
        const float* bc = dbc + bl*64 + DT_RANK;
        #pragma unroll
        for (int s=0;s<16;s++){
            float a = __expf(dtv*Ae[s]);
            h[s] = h[s]*a + dtx*bc[s];
            Pr[s] *= a;
        }
    }
    size_t base = ((size_t)(b*NC + c)*16)*1024 + e;
    #pragma unroll
    for (int s=0;s<16;s++){ S[base + (size_t)s*1024] = h[s]; P[base + (size_t)s*1024] = Pr[s]; }
}

// ---------------- scan pass M ----------------
__global__ __launch_bounds__(256) void scan_m(const float* __restrict__ S,
                                              const float* __restrict__ P,
                                              float* __restrict__ H0)
{
    int idx = blockIdx.x*256 + threadIdx.x;
    int e = idx & 1023;
    int s = (idx >> 10) & 15;
    int b = idx >> 14;
    float h = 0.f;
    for (int c=0;c<NC;c++){
        size_t off = ((size_t)(b*NC+c)*16 + s)*1024 + e;
        H0[off] = h;
        h = S[off] + P[off]*h;
    }
}

// ---------------- scan pass B ----------------
__global__ __launch_bounds__(256) void scan_b(const float* dt_in,
                                              const float* __restrict__ xc,
                                              const float* __restrict__ dbc,
                                              const float* __restrict__ z,
                                              const float* __restrict__ A_log,
                                              const float* __restrict__ Dpv,
                                              const float* __restrict__ H0,
                                              float* y)
{
    int e = blockIdx.x*256 + threadIdx.x;
    int c = blockIdx.y, b = blockIdx.z;
    float Ae[16], h[16];
    size_t base = ((size_t)(b*NC + c)*16)*1024 + e;
    #pragma unroll
    for (int s=0;s<16;s++){ Ae[s] = -expf(A_log[e*16+s]); h[s] = H0[base + (size_t)s*1024]; }
    float dpe = Dpv[e];
    int bl0 = b*SEQLEN + c*CH;
    for (int t=0;t<CH;t++){
        size_t bl = bl0 + t;
        float dtv = dt_in[bl*1024 + e];
        float xv  = xc[bl*1024 + e];
        float dtx = dtv*xv;
        const float* bc = dbc + bl*64 + DT_RANK;
        float yv = 0.f;
        #pragma unroll
        for (int s=0;s<16;s++){
            float a = __expf(dtv*Ae[s]);
            h[s] = h[s]*a + dtx*bc[s];
            yv += h[s]*bc[16+s];
        }
        yv += dpe*xv;
        float zv = z[bl*1024 + e];
        y[bl*1024 + e] = yv * silu_f(zv);
    }
}

// ---------------- LayerNorm over D=512 ----------------
__global__ __launch_bounds__(256) void layernorm_kernel(const float* __restrict__ x,
                                                        const float* __restrict__ g,
                                                        const float* __restrict__ bta,
                                                        float* __restrict__ out)
{
    int row = blockIdx.x;
    int tid = threadIdx.x;
    const float* xr = x + (size_t)row*512;
    float v0 = xr[tid], v1 = xr[tid+256];
    float s = v0 + v1;
    #pragma unroll
    for (int off=32; off>0; off>>=1) s += __shfl_down(s, off);
    __shared__ float red[8];
    int wid = tid>>6, lane = tid&63;
    if (lane==0) red[wid] = s;
    __syncthreads();
    if (tid==0){ float t=0; for(int i=0;i<4;i++) t+=red[i]; red[4] = t*(1.f/512.f); }
    __syncthreads();
    float m = red[4];
    float d0 = v0-m, d1 = v1-m;
    float q = d0*d0 + d1*d1;
    #pragma unroll
    for (int off=32; off>0; off>>=1) q += __shfl_down(q, off);
    if (lane==0) red[wid] = q;
    __syncthreads();
    if (tid==0){ float t=0; for(int i=0;i<4;i++) t+=red[i]; red[5] = t*(1.f/512.f); }
    __syncthreads();
    float inv = 1.f / sqrtf(red[5] + 1e-5f);
    out[(size_t)row*512 + tid]     = d0*inv*g[tid]     + bta[tid];
    out[(size_t)row*512 + tid+256] = d1*inv*g[tid+256] + bta[tid+256];
}

extern "C" void kernel_launch(void* const* d_in, const int* in_sizes, int n_in,
                              void* d_out, int out_size, void* d_ws, size_t ws_size,
                              hipStream_t stream)
{
    const float* ecg  = (const float*)d_in[0];
    const float* Wp   = (const float*)d_in[1];
    const float* bp   = (const float*)d_in[2];
    const float* Win  = (const float*)d_in[3];
    const float* convw= (const float*)d_in[4];
    const float* convb= (const float*)d_in[5];
    const float* Wx   = (const float*)d_in[6];
    const float* Wdt  = (const float*)d_in[7];
    const float* bdt  = (const float*)d_in[8];
    const float* A_log= (const float*)d_in[9];
    const float* Dp   = (const float*)d_in[10];
    const float* Wout = (const float*)d_in[11];
    const float* ln_g = (const float*)d_in[12];
    const float* ln_b = (const float*)d_in[13];
    float* out = (float*)d_out;   // persistent x buffer (B,L,512)

    int NBC = 8;
    while (NBC > 1 && (size_t)NBC*9068800ull*4ull > ws_size) NBC >>= 1;

    float* ws  = (float*)d_ws;
    size_t MT  = (size_t)NBC*SEQLEN;
    float* Ab  = ws;                      // MT*1024   (x_conv pre-act, then z)
    float* Bx  = Ab + MT*1024;            // MT*1024   (xc)
    float* Cb  = Bx + MT*1024;            // MT*1024   (dt, then y in-place)
    float* dbc = Cb + MT*1024;            // MT*64
    float* Sb  = dbc + MT*64;
    float* Pb  = Sb + (size_t)NBC*409600;
    float* H0  = Pb + (size_t)NBC*409600;

    proj_kernel<<<(BL*512)/256,256,0,stream>>>(ecg, Wp, bp, out);

    const int M = NBC*SEQLEN;
    const int mtiles128 = (M+127)/128;

    for (int l=0; l<N_LAYERS; ++l) {
        const float* Winl = Win + (size_t)l*2048*512;
        for (int b0=0; b0<BATCH; b0+=NBC) {
            float* xchunk = out + (size_t)b0*SEQLEN*512;
            // 1) x_conv pre-activation = x @ Win[0:1024]^T   (MFMA split-bf16)
            gemm_bf16x2<<<dim3(1024/128, mtiles128),256,0,stream>>>(xchunk,
                Winl, Ab, M, 1024, 512);
            // 2) xc = silu(causal dwconv(x_conv))
            conv_silu_kernel<<<(M*1024)/256,256,0,stream>>>(Ab,
                convw + (size_t)l*1024*4, convb + (size_t)l*1024, Bx, M);
            // 3) z = x @ Win[1024:2048]^T  (reuse Ab)
            gemm_bf16x2<<<dim3(1024/128, mtiles128),256,0,stream>>>(xchunk,
                Winl + (size_t)1024*512, Ab, M, 1024, 512);
            // 4) dbc = xc @ Wx^T   (small, f32)
            gemm_f32<0><<<dim3(1, mtiles128),256,0,stream>>>(Bx, 1024,
                Wx + (size_t)l*64*1024, nullptr, dbc, M, 64, 1024);
            // 5) dt = softplus(dbc[:, :32] @ Wdt^T + bdt)  (small K, f32)
            gemm_f32<1><<<dim3(1024/64, mtiles128),256,0,stream>>>(dbc, 64,
                Wdt + (size_t)l*1024*32, bdt + (size_t)l*1024, Cb, M, 1024, 32);
            // 6) chunk-parallel selective scan + D-skip + silu(z) gate
            scan_a<<<dim3(4,NC,NBC),256,0,stream>>>(Cb, Bx, dbc,
                A_log + (size_t)l*1024*16, Sb, Pb);
            scan_m<<<NBC*64,256,0,stream>>>(Sb, Pb, H0);
            scan_b<<<dim3(4,NC,NBC),256,0,stream>>>(Cb, Bx, dbc, Ab,
                A_log + (size_t)l*1024*16, Dp + (size_t)l*1024, H0, Cb);
            // 7) x = y @ Wout^T   (MFMA split-bf16)
            gemm_bf16x2<<<dim3(512/128, mtiles128),256,0,stream>>>(Cb,
                Wout + (size_t)l*512*1024, xchunk, M, 512, 1024);
            // 8) LayerNorm in place
            layernorm_kernel<<<M,256,0,stream>>>(xchunk, ln_g + (size_t)l*512,
                ln_b + (size_t)l*512, xchunk);
        }
    }
}

// Round 4
// 3325.864 us; speedup vs baseline: 1.9207x; 1.4965x over previous
//
#include <hip/hip_runtime.h>
#include <cstdint>
#include <cstddef>

#define D_MODEL 512
#define D_STATE 16
#define D_INNER 1024
#define DT_RANK 32
#define D_CONV 4
#define N_LAYERS 4
#define NUM_LEADS 12
#define BATCH 8
#define SEQLEN 2500
#define BL (BATCH*SEQLEN)   // 20000
#define NC 50               // scan chunks per sequence
#define CH 50               // steps per chunk (NC*CH == SEQLEN)

typedef __attribute__((ext_vector_type(8))) short bf16x8;
typedef __attribute__((ext_vector_type(4))) float f32x4;

__device__ __forceinline__ float softplus_f(float x){
    return x > 0.f ? x + log1pf(expf(-x)) : log1pf(expf(x));
}
__device__ __forceinline__ float silu_f(float x){
    return x / (1.f + expf(-x));
}

// ---------------- projection: x[b,l,d] = sum_c ecg[b,c,l]*Wp[d,c] + bp[d] ----------------
__global__ __launch_bounds__(256) void proj_kernel(const float* __restrict__ ecg,
                                                   const float* __restrict__ Wp,
                                                   const float* __restrict__ bp,
                                                   float* __restrict__ x)
{
    int idx = blockIdx.x*256 + threadIdx.x;      // over BL*512
    int d  = idx & 511;
    int bl = idx >> 9;
    if (bl >= BL) return;
    int b = bl / SEQLEN, l = bl % SEQLEN;
    const float* e = ecg + (size_t)b*NUM_LEADS*SEQLEN + l;
    const float* w = Wp + d*NUM_LEADS;
    float acc = bp[d];
    #pragma unroll
    for (int c=0;c<NUM_LEADS;c++) acc += e[(size_t)c*SEQLEN]*w[c];
    x[idx] = acc;
}

// ---------------- split-bf16 MFMA GEMM: C[M,N] = A[M,K] * W[N,K]^T ----------------
// x = hi + lo (bf16 each); C ≈ Ah*Wh + Ah*Wl + Al*Wh (3 MFMA terms).
// Tile 128x128, BK=64, 4 waves; register-prefetch pipeline hides global latency.
__device__ __forceinline__ void split_store(ushort* __restrict__ Hi, ushort* __restrict__ Lo,
                                            int idx, float4 v)
{
    uint u0=__float_as_uint(v.x), u1=__float_as_uint(v.y);
    uint u2=__float_as_uint(v.z), u3=__float_as_uint(v.w);
    float h0=__uint_as_float(u0&0xffff0000u), h1=__uint_as_float(u1&0xffff0000u);
    float h2=__uint_as_float(u2&0xffff0000u), h3=__uint_as_float(u3&0xffff0000u);
    uint l0=__float_as_uint(v.x-h0)>>16, l1=__float_as_uint(v.y-h1)>>16;
    uint l2=__float_as_uint(v.z-h2)>>16, l3=__float_as_uint(v.w-h3)>>16;
    uint2 hp = make_uint2((u0>>16)|(u1&0xffff0000u), (u2>>16)|(u3&0xffff0000u));
    uint2 lp = make_uint2(l0|(l1<<16), l2|(l3<<16));
    *(uint2*)&Hi[idx] = hp;
    *(uint2*)&Lo[idx] = lp;
}

__global__ __launch_bounds__(256,2) void gemm_bf16x2(const float* __restrict__ A,
                                                     const float* __restrict__ W,
                                                     float* __restrict__ C,
                                                     int M, int N, int K)
{
    __shared__ ushort Ah[128*64];
    __shared__ ushort Al[128*64];
    __shared__ ushort Wh[128*64];
    __shared__ ushort Wl[128*64];
    const int tid  = threadIdx.x;
    const int row0 = blockIdx.y*128;
    const int col0 = blockIdx.x*128;
    const int wid  = tid>>6, lane = tid&63;
    const int wr = wid>>1, wc = wid&1;
    const int l15 = lane&15, l4 = lane>>4;
    const int tr = tid>>4, c4 = tid&15;     // staging coords: r = i*16+tr, col = c4*4

    f32x4 zero = {0.f,0.f,0.f,0.f};
    f32x4 acc[4][4];
    #pragma unroll
    for (int i=0;i<4;i++)
        #pragma unroll
        for (int j=0;j<4;j++) acc[i][j] = zero;

    float4 pa[8], pw[8];
    // prologue: load K-step 0
    #pragma unroll
    for (int i=0;i<8;i++){
        int r = i*16 + tr;
        int gr = row0 + r;
        pa[i] = (gr < M) ? *(const float4*)(A + (size_t)gr*K + c4*4)
                         : make_float4(0.f,0.f,0.f,0.f);
        pw[i] = *(const float4*)(W + (size_t)(col0+r)*K + c4*4);
    }

    const int NT = K >> 6;
    for (int t=0; t<NT; t++){
        // ---- write current regs to LDS (split hi/lo, swizzled) ----
        #pragma unroll
        for (int i=0;i<8;i++){
            int r  = i*16 + tr;
            int sp = (c4>>1) ^ (r&7);
            int idx = r*64 + sp*8 + (c4&1)*4;
            split_store(Ah, Al, idx, pa[i]);
            split_store(Wh, Wl, idx, pw[i]);
        }
        __syncthreads();
        // ---- issue next K-step's global loads (latency hides under compute) ----
        if (t+1 < NT){
            int kk = (t+1)<<6;
            #pragma unroll
            for (int i=0;i<8;i++){
                int r = i*16 + tr;
                int gr = row0 + r;
                pa[i] = (gr < M) ? *(const float4*)(A + (size_t)gr*K + kk + c4*4)
                                 : make_float4(0.f,0.f,0.f,0.f);
                pw[i] = *(const float4*)(W + (size_t)(col0+r)*K + kk + c4*4);
            }
        }
        // ---- compute: 2 K-sub-steps of 32, 16 frags/wave, 3 MFMA terms ----
        #pragma unroll
        for (int ks=0; ks<2; ks++){
            bf16x8 ah[4], al[4], bh[4], blv[4];
            #pragma unroll
            for (int i=0;i<4;i++){
                int r = wr*64 + i*16 + l15;
                int sp = (ks*4 + l4) ^ (r&7);
                int idx = r*64 + sp*8;
                ah[i] = *(const bf16x8*)&Ah[idx];
                al[i] = *(const bf16x8*)&Al[idx];
            }
            #pragma unroll
            for (int j=0;j<4;j++){
                int r = wc*64 + j*16 + l15;
                int sp = (ks*4 + l4) ^ (r&7);
                int idx = r*64 + sp*8;
                bh[j] = *(const bf16x8*)&Wh[idx];
                blv[j] = *(const bf16x8*)&Wl[idx];
            }
            #pragma unroll
            for (int i=0;i<4;i++)
                #pragma unroll
                for (int j=0;j<4;j++){
                    acc[i][j] = __builtin_amdgcn_mfma_f32_16x16x32_bf16(ah[i], bh[j], acc[i][j], 0,0,0);
                    acc[i][j] = __builtin_amdgcn_mfma_f32_16x16x32_bf16(ah[i], blv[j], acc[i][j], 0,0,0);
                    acc[i][j] = __builtin_amdgcn_mfma_f32_16x16x32_bf16(al[i], bh[j], acc[i][j], 0,0,0);
                }
        }
        __syncthreads();
    }
    // ---- epilogue: D layout col=lane&15, row=(lane>>4)*4+reg ----
    #pragma unroll
    for (int i=0;i<4;i++){
        int rb = row0 + wr*64 + i*16 + l4*4;
        #pragma unroll
        for (int j=0;j<4;j++){
            int gc = col0 + wc*64 + j*16 + l15;
            #pragma unroll
            for (int q=0;q<4;q++){
                int grow = rb + q;
                if (grow < M) C[(size_t)grow*N + gc] = acc[i][j][q];
            }
        }
    }
}

// ---------------- skinny f32 GEMM for dbc: BM=32, BN=64, BK=32 ----------------
__global__ __launch_bounds__(256) void gemm_f32_skinny(const float* __restrict__ A, int lda,
                                                       const float* __restrict__ W,
                                                       float* __restrict__ C,
                                                       int M, int N, int K)
{
    __shared__ float As[32][33];
    __shared__ float Ws[32][68];
    const int tid = threadIdx.x;
    const int row0 = blockIdx.y*32;
    const int ty = tid>>4, tx = tid&15;      // 16x16, each 2x4 outputs
    float acc[2][4] = {};

    for (int kk=0; kk<K; kk+=32) {
        {
            int r = tid>>3, cc4 = tid&7;
            int gr = row0 + r;
            float4 v = make_float4(0.f,0.f,0.f,0.f);
            if (gr < M) v = *(const float4*)(A + (size_t)gr*lda + kk + cc4*4);
            As[cc4*4+0][r]=v.x; As[cc4*4+1][r]=v.y; As[cc4*4+2][r]=v.z; As[cc4*4+3][r]=v.w;
        }
        #pragma unroll
        for (int i=0;i<2;i++){
            int idx = i*256 + tid;
            int r = idx>>3, cc4 = idx&7;
            float4 v = *(const float4*)(W + (size_t)r*K + kk + cc4*4);
            Ws[cc4*4+0][r]=v.x; Ws[cc4*4+1][r]=v.y; Ws[cc4*4+2][r]=v.z; Ws[cc4*4+3][r]=v.w;
        }
        __syncthreads();
        #pragma unroll
        for (int k=0;k<32;k++){
            float a0 = As[k][ty*2], a1 = As[k][ty*2+1];
            float4 bv = *(const float4*)&Ws[k][tx*4];
            acc[0][0]+=a0*bv.x; acc[0][1]+=a0*bv.y; acc[0][2]+=a0*bv.z; acc[0][3]+=a0*bv.w;
            acc[1][0]+=a1*bv.x; acc[1][1]+=a1*bv.y; acc[1][2]+=a1*bv.z; acc[1][3]+=a1*bv.w;
        }
        __syncthreads();
    }
    #pragma unroll
    for (int i=0;i<2;i++){
        int gr = row0 + ty*2 + i;
        if (gr >= M) continue;
        float4 o = make_float4(acc[i][0],acc[i][1],acc[i][2],acc[i][3]);
        *(float4*)(C + (size_t)gr*N + tx*4) = o;
    }
}

// ---------------- generic f32 GEMM (kept for dt): C = act(A*W^T + bias) ----------------
template<int ACT>
__global__ __launch_bounds__(256) void gemm_f32(const float* __restrict__ A, int lda,
                                                const float* __restrict__ W,
                                                const float* __restrict__ bias,
                                                float* __restrict__ C,
                                                int M, int N, int K)
{
    constexpr int BM=128, BN=64, BK=16;
    __shared__ float As[BK][BM+4];
    __shared__ float Ws[BK][BN+4];
    const int tid = threadIdx.x;
    const int row0 = blockIdx.y*BM;
    const int col0 = blockIdx.x*BN;
    const int ty = tid>>4, tx = tid&15;
    const int lr = tid>>2;
    const int lk = (tid&3)<<2;
    float acc[8][4] = {};

    for (int kk=0; kk<K; kk+=BK) {
        #pragma unroll
        for (int h=0; h<2; ++h) {
            int r = lr + h*64;
            int gr = row0 + r;
            float4 v = make_float4(0.f,0.f,0.f,0.f);
            if (gr < M) v = *(const float4*)(A + (size_t)gr*lda + kk + lk);
            As[lk+0][r]=v.x; As[lk+1][r]=v.y; As[lk+2][r]=v.z; As[lk+3][r]=v.w;
        }
        {
            int gc = col0 + lr;
            float4 v = *(const float4*)(W + (size_t)gc*K + kk + lk);
            Ws[lk+0][lr]=v.x; Ws[lk+1][lr]=v.y; Ws[lk+2][lr]=v.z; Ws[lk+3][lr]=v.w;
        }
        __syncthreads();
        #pragma unroll
        for (int k=0;k<BK;k++){
            float4 a0 = *(const float4*)&As[k][ty*8];
            float4 a1 = *(const float4*)&As[k][ty*8+4];
            float4 bv = *(const float4*)&Ws[k][tx*4];
            float a[8] = {a0.x,a0.y,a0.z,a0.w,a1.x,a1.y,a1.z,a1.w};
            float bb[4] = {bv.x,bv.y,bv.z,bv.w};
            #pragma unroll
            for (int i=0;i<8;i++)
                #pragma unroll
                for (int j=0;j<4;j++)
                    acc[i][j] += a[i]*bb[j];
        }
        __syncthreads();
    }
    #pragma unroll
    for (int i=0;i<8;i++){
        int gr = row0 + ty*8 + i;
        if (gr >= M) continue;
        float4 o;
        float* op = &o.x;
        #pragma unroll
        for (int j=0;j<4;j++){
            int gc = col0 + tx*4 + j;
            float v = acc[i][j];
            if (ACT==1) v = softplus_f(v + bias[gc]);
            op[j] = v;
        }
        *(float4*)(C + (size_t)gr*N + col0 + tx*4) = o;
    }
}

// ---------------- causal dwconv + silu: 4 timesteps x 4 channels per thread ----------------
__global__ __launch_bounds__(256) void conv_silu_v2(const float* __restrict__ xin,
                                                    const float* __restrict__ w,
                                                    const float* __restrict__ cb,
                                                    float* __restrict__ xc)
{
    int t4 = blockIdx.x;
    int e  = threadIdx.x*4;
    int bl0 = t4*4;
    int l0  = bl0 % SEQLEN;
    float4 w0 = *(const float4*)(w + (e+0)*4);
    float4 w1 = *(const float4*)(w + (e+1)*4);
    float4 w2 = *(const float4*)(w + (e+2)*4);
    float4 w3 = *(const float4*)(w + (e+3)*4);
    float4 bias = *(const float4*)(cb + e);
    float4 xb[7];
    #pragma unroll
    for (int j=0;j<7;j++){
        int off = j-3;
        xb[j] = (l0 + off >= 0) ? *(const float4*)(xin + (size_t)(bl0+off)*1024 + e)
                                : make_float4(0.f,0.f,0.f,0.f);
    }
    #pragma unroll
    for (int j=0;j<4;j++){
        float4 o;
        o.x = bias.x + w0.x*xb[j].x + w0.y*xb[j+1].x + w0.z*xb[j+2].x + w0.w*xb[j+3].x;
        o.y = bias.y + w1.x*xb[j].y + w1.y*xb[j+1].y + w1.z*xb[j+2].y + w1.w*xb[j+3].y;
        o.z = bias.z + w2.x*xb[j].z + w2.y*xb[j+1].z + w2.z*xb[j+2].z + w2.w*xb[j+3].z;
        o.w = bias.w + w3.x*xb[j].w + w3.y*xb[j+1].w + w3.z*xb[j+2].w + w3.w*xb[j+3].w;
        o.x = silu_f(o.x); o.y = silu_f(o.y); o.z = silu_f(o.z); o.w = silu_f(o.w);
        *(float4*)(xc + (size_t)(bl0+j)*1024 + e) = o;
    }
}

// ---------------- scan pass A: local scan from h=0; store final state S, product P ----------------
__global__ __launch_bounds__(256) void scan_a(const float* __restrict__ dt,
                                              const float* __restrict__ xc,
                                              const float* __restrict__ dbc,
                                              const float* __restrict__ A_log,
                                              float* __restrict__ S, float* __restrict__ P)
{
    int e = blockIdx.x*256 + threadIdx.x;
    int c = blockIdx.y, b = blockIdx.z;
    float Ae[16], h[16], Pr[16];
    #pragma unroll
    for (int s=0;s<16;s++){ Ae[s] = -expf(A_log[e*16+s]); h[s]=0.f; Pr[s]=1.f; }
    int bl0 = b*SEQLEN + c*CH;
    size_t pe = (size_t)bl0*1024 + e;
    const float* bcp = dbc + (size_t)bl0*64 + DT_RANK;
    float dtv = dt[pe], xv = xc[pe];
    float4 b0 = *(const float4*)(bcp+0), b1 = *(const float4*)(bcp+4);
    float4 b2 = *(const float4*)(bcp+8), b3 = *(const float4*)(bcp+12);
    for (int t=0;t<CH;t++){
        float dtn=0.f, xvn=0.f;
        float4 n0=b0,n1=b1,n2=b2,n3=b3;
        if (t+1<CH){
            dtn = dt[pe+1024]; xvn = xc[pe+1024];
            n0 = *(const float4*)(bcp+64); n1 = *(const float4*)(bcp+68);
            n2 = *(const float4*)(bcp+72); n3 = *(const float4*)(bcp+76);
        }
        float dtx = dtv*xv;
        float bcv[16] = {b0.x,b0.y,b0.z,b0.w,b1.x,b1.y,b1.z,b1.w,
                         b2.x,b2.y,b2.z,b2.w,b3.x,b3.y,b3.z,b3.w};
        #pragma unroll
        for (int s=0;s<16;s++){
            float a = __expf(dtv*Ae[s]);
            h[s] = h[s]*a + dtx*bcv[s];
            Pr[s] *= a;
        }
        dtv=dtn; xv=xvn; b0=n0; b1=n1; b2=n2; b3=n3;
        pe += 1024; bcp += 64;
    }
    size_t base = ((size_t)(b*NC + c)*16)*1024 + e;
    #pragma unroll
    for (int s=0;s<16;s++){ S[base + (size_t)s*1024] = h[s]; P[base + (size_t)s*1024] = Pr[s]; }
}

// ---------------- scan pass M: sequential combine -> initial state per chunk ----------------
__global__ __launch_bounds__(256) void scan_m(const float* __restrict__ S,
                                              const float* __restrict__ P,
                                              float* __restrict__ H0)
{
    int idx = blockIdx.x*256 + threadIdx.x;
    int e = idx & 1023;
    int s = (idx >> 10) & 15;
    int b = idx >> 14;
    float h = 0.f;
    for (int c=0;c<NC;c++){
        size_t off = ((size_t)(b*NC+c)*16 + s)*1024 + e;
        H0[off] = h;
        h = S[off] + P[off]*h;
    }
}

// ---------------- scan pass B: scan with init states; fused D-skip + silu(z) gate ----------------
__global__ __launch_bounds__(256) void scan_b(const float* dt_in,
                                              const float* __restrict__ xc,
                                              const float* __restrict__ dbc,
                                              const float* __restrict__ z,
                                              const float* __restrict__ A_log,
                                              const float* __restrict__ Dpv,
                                              const float* __restrict__ H0,
                                              float* y)
{
    int e = blockIdx.x*256 + threadIdx.x;
    int c = blockIdx.y, b = blockIdx.z;
    float Ae[16], h[16];
    size_t base = ((size_t)(b*NC + c)*16)*1024 + e;
    #pragma unroll
    for (int s=0;s<16;s++){ Ae[s] = -expf(A_log[e*16+s]); h[s] = H0[base + (size_t)s*1024]; }
    float dpe = Dpv[e];
    int bl0 = b*SEQLEN + c*CH;
    size_t pe = (size_t)bl0*1024 + e;
    const float* bcp = dbc + (size_t)bl0*64 + DT_RANK;
    float dtv = dt_in[pe], xv = xc[pe], zv = z[pe];
    float4 b0 = *(const float4*)(bcp+0),  b1 = *(const float4*)(bcp+4);
    float4 b2 = *(const float4*)(bcp+8),  b3 = *(const float4*)(bcp+12);
    float4 c0 = *(const float4*)(bcp+16), c1 = *(const float4*)(bcp+20);
    float4 c2 = *(const float4*)(bcp+24), c3 = *(const float4*)(bcp+28);
    for (int t=0;t<CH;t++){
        float dtn=0.f, xvn=0.f, zvn=0.f;
        float4 n0=b0,n1=b1,n2=b2,n3=b3,m0=c0,m1=c1,m2=c2,m3=c3;
        if (t+1<CH){
            dtn = dt_in[pe+1024]; xvn = xc[pe+1024]; zvn = z[pe+1024];
            n0 = *(const float4*)(bcp+64); n1 = *(const float4*)(bcp+68);
            n2 = *(const float4*)(bcp+72); n3 = *(const float4*)(bcp+76);
            m0 = *(const float4*)(bcp+80); m1 = *(const float4*)(bcp+84);
            m2 = *(const float4*)(bcp+88); m3 = *(const float4*)(bcp+92);
        }
        float dtx = dtv*xv;
        float bcv[16] = {b0.x,b0.y,b0.z,b0.w,b1.x,b1.y,b1.z,b1.w,
                         b2.x,b2.y,b2.z,b2.w,b3.x,b3.y,b3.z,b3.w};
        float ccv[16] = {c0.x,c0.y,c0.z,c0.w,c1.x,c1.y,c1.z,c1.w,
                         c2.x,c2.y,c2.z,c2.w,c3.x,c3.y,c3.z,c3.w};
        float yv = 0.f;
        #pragma unroll
        for (int s=0;s<16;s++){
            float a = __expf(dtv*Ae[s]);
            h[s] = h[s]*a + dtx*bcv[s];
            yv += h[s]*ccv[s];
        }
        yv += dpe*xv;
        y[pe] = yv * silu_f(zv);
        dtv=dtn; xv=xvn; zv=zvn;
        b0=n0;b1=n1;b2=n2;b3=n3; c0=m0;c1=m1;c2=m2;c3=m3;
        pe += 1024; bcp += 64;
    }
}

// ---------------- LayerNorm: one wave per row of 512 ----------------
__global__ __launch_bounds__(256) void layernorm_wave(const float* __restrict__ x,
                                                      const float* __restrict__ g,
                                                      const float* __restrict__ bta,
                                                      float* __restrict__ out)
{
    int row  = blockIdx.x*4 + (threadIdx.x>>6);
    int lane = threadIdx.x & 63;
    const float* xr = x + (size_t)row*512;
    float4 v0 = *(const float4*)(xr + lane*4);
    float4 v1 = *(const float4*)(xr + 256 + lane*4);
    float s = v0.x+v0.y+v0.z+v0.w + v1.x+v1.y+v1.z+v1.w;
    #pragma unroll
    for (int off=32; off>0; off>>=1) s += __shfl_down(s, off);
    float m = __shfl(s, 0) * (1.f/512.f);
    float d0=v0.x-m, d1=v0.y-m, d2=v0.z-m, d3=v0.w-m;
    float d4=v1.x-m, d5=v1.y-m, d6=v1.z-m, d7=v1.w-m;
    float q = d0*d0+d1*d1+d2*d2+d3*d3+d4*d4+d5*d5+d6*d6+d7*d7;
    #pragma unroll
    for (int off=32; off>0; off>>=1) q += __shfl_down(q, off);
    float inv = 1.f / sqrtf(__shfl(q, 0)*(1.f/512.f) + 1e-5f);
    float4 g0 = *(const float4*)(g + lane*4),   g1 = *(const float4*)(g + 256 + lane*4);
    float4 t0 = *(const float4*)(bta + lane*4), t1 = *(const float4*)(bta + 256 + lane*4);
    float4 o0 = make_float4(d0*inv*g0.x+t0.x, d1*inv*g0.y+t0.y, d2*inv*g0.z+t0.z, d3*inv*g0.w+t0.w);
    float4 o1 = make_float4(d4*inv*g1.x+t1.x, d5*inv*g1.y+t1.y, d6*inv*g1.z+t1.z, d7*inv*g1.w+t1.w);
    *(float4*)(out + (size_t)row*512 + lane*4)       = o0;
    *(float4*)(out + (size_t)row*512 + 256 + lane*4) = o1;
}

extern "C" void kernel_launch(void* const* d_in, const int* in_sizes, int n_in,
                              void* d_out, int out_size, void* d_ws, size_t ws_size,
                              hipStream_t stream)
{
    const float* ecg  = (const float*)d_in[0];
    const float* Wp   = (const float*)d_in[1];
    const float* bp   = (const float*)d_in[2];
    const float* Win  = (const float*)d_in[3];
    const float* convw= (const float*)d_in[4];
    const float* convb= (const float*)d_in[5];
    const float* Wx   = (const float*)d_in[6];
    const float* Wdt  = (const float*)d_in[7];
    const float* bdt  = (const float*)d_in[8];
    const float* A_log= (const float*)d_in[9];
    const float* Dp   = (const float*)d_in[10];
    const float* Wout = (const float*)d_in[11];
    const float* ln_g = (const float*)d_in[12];
    const float* ln_b = (const float*)d_in[13];
    float* out = (float*)d_out;   // persistent x buffer (B,L,512)

    // per-batch-elem scratch floats: 2500*(3*1024+64) + 3*NC*16*1024 = 10,297,600
    int NBC = 8;
    while (NBC > 1 && (size_t)NBC*10297600ull*4ull > ws_size) NBC >>= 1;

    float* ws  = (float*)d_ws;
    size_t MT  = (size_t)NBC*SEQLEN;
    float* Ab  = ws;                      // MT*1024   (x_conv pre-act, then z)
    float* Bx  = Ab + MT*1024;            // MT*1024   (xc)
    float* Cb  = Bx + MT*1024;            // MT*1024   (dt, then y in-place)
    float* dbc = Cb + MT*1024;            // MT*64
    float* Sb  = dbc + MT*64;             // NBC*NC*16*1024
    float* Pb  = Sb + (size_t)NBC*NC*16*1024;
    float* H0  = Pb + (size_t)NBC*NC*16*1024;

    proj_kernel<<<(BL*512)/256,256,0,stream>>>(ecg, Wp, bp, out);

    const int M = NBC*SEQLEN;
    const int mtiles128 = (M+127)/128;

    for (int l=0; l<N_LAYERS; ++l) {
        const float* Winl = Win + (size_t)l*2048*512;
        for (int b0=0; b0<BATCH; b0+=NBC) {
            float* xchunk = out + (size_t)b0*SEQLEN*512;
            // 1) x_conv pre-activation = x @ Win[0:1024]^T   (MFMA split-bf16)
            gemm_bf16x2<<<dim3(1024/128, mtiles128),256,0,stream>>>(xchunk,
                Winl, Ab, M, 1024, 512);
            // 2) xc = silu(causal dwconv(x_conv))
            conv_silu_v2<<<M/4,256,0,stream>>>(Ab,
                convw + (size_t)l*1024*4, convb + (size_t)l*1024, Bx);
            // 3) z = x @ Win[1024:2048]^T  (reuse Ab)
            gemm_bf16x2<<<dim3(1024/128, mtiles128),256,0,stream>>>(xchunk,
                Winl + (size_t)1024*512, Ab, M, 1024, 512);
            // 4) dbc = xc @ Wx^T   (skinny f32, 625 blocks)
            gemm_f32_skinny<<<dim3(1,(M+31)/32),256,0,stream>>>(Bx, 1024,
                Wx + (size_t)l*64*1024, dbc, M, 64, 1024);
            // 5) dt = softplus(dbc[:, :32] @ Wdt^T + bdt)
            gemm_f32<1><<<dim3(1024/64, mtiles128),256,0,stream>>>(dbc, 64,
                Wdt + (size_t)l*1024*32, bdt + (size_t)l*1024, Cb, M, 1024, 32);
            // 6) chunk-parallel selective scan + D-skip + silu(z) gate
            scan_a<<<dim3(4,NC,NBC),256,0,stream>>>(Cb, Bx, dbc,
                A_log + (size_t)l*1024*16, Sb, Pb);
            scan_m<<<NBC*64,256,0,stream>>>(Sb, Pb, H0);
            scan_b<<<dim3(4,NC,NBC),256,0,stream>>>(Cb, Bx, dbc, Ab,
                A_log + (size_t)l*1024*16, Dp + (size_t)l*1024, H0, Cb);
            // 7) x = y @ Wout^T   (MFMA split-bf16)
            gemm_bf16x2<<<dim3(512/128, mtiles128),256,0,stream>>>(Cb,
                Wout + (size_t)l*512*1024, xchunk, M, 512, 1024);
            // 8) LayerNorm in place (one wave per row)
            layernorm_wave<<<M/4,256,0,stream>>>(xchunk, ln_g + (size_t)l*512,
                ln_b + (size_t)l*512, xchunk);
        }
    }
}